// Round 9
// baseline (647.099 us; speedup 1.0000x reference)
//
#include <hip/hip_runtime.h>
#include <hip/hip_bf16.h>
#include <stdint.h>

// LSTMCell fused: g = hx @ W + b (M=8192,K=2048,N=7*2048) + gate math.
// R9: 16-wave (4 waves/SIMD) proven-overlap regime, with A-operand moved
// OUT of LDS (direct coalesced global loads from bf16 image). LDS serves
// B only: 112 b128-reads + 14KB glds-writes per step (~1510 cyc) vs R4's
// ~2100. Depth-2 glds pipeline, 3 LDS buffers, one vmcnt(1)+barrier/step.

#define B_SZ 8192
#define D_SZ 2048
#define H_SZ 2048
#define NG   7
#define NW   (NG * H_SZ)          // 14336
#define BM   256
#define BN   32
#define BK   32
#define NKST (D_SZ / BK)          // 64
#define NBX  (B_SZ / BM)          // 32
#define NBY  (H_SZ / BN)          // 64

// bf16 tile images in ws:
//  W' : [by(64)][ks(64)] -> 224 rows x 32 k bf16 = 14336 B (XOR-swizzled)
//  hx': [bx(32)][ks(64)] -> 256 rows x 32 k bf16 = 16384 B (PLAIN layout --
//       A is read straight to VGPRs now; no banks to swizzle for)
#define WB_BYTES   ((size_t)NBY * NKST * 14336)   // 58,720,256
#define HXB_OFF    WB_BYTES
#define HXB_BYTES  ((size_t)NBX * NKST * 16384)   // 33,554,432
#define WS_NEEDED  (WB_BYTES + HXB_BYTES)         // 92,274,688

typedef __attribute__((ext_vector_type(8))) short bf16x8;
typedef __attribute__((ext_vector_type(4))) float f32x4;

__device__ __forceinline__ uint32_t cvtpk(float lo, float hi) {
    uint32_t r;
    asm("v_cvt_pk_bf16_f32 %0, %1, %2" : "=v"(r) : "v"(lo), "v"(hi));
    return r;
}
__device__ __forceinline__ void glds16(const void* g, void* l) {
    __builtin_amdgcn_global_load_lds(
        (const __attribute__((address_space(1))) uint32_t*)g,
        (__attribute__((address_space(3))) uint32_t*)l, 16, 0, 0);
}
__device__ __forceinline__ float sigmoidf_(float x) {
    return 1.0f / (1.0f + __expf(-x));
}
__device__ __forceinline__ float tanhf_(float x) {
    float ax = fabsf(x);
    float e = __expf(2.0f * ax);
    float t = 1.0f - 2.0f / (e + 1.0f);
    return copysignf(t, x);
}
__device__ __forceinline__ float softplusf_(float x) {
    return (x > 30.0f) ? x : __logf(1.0f + __expf(x));
}

// ---------------- convert W -> W' (bf16, transposed, swizzled) -------------
__global__ __launch_bounds__(896) void conv_w(const float* __restrict__ W,
                                              char* __restrict__ wb)
{
    const int by = blockIdx.x >> 6;
    const int ks = blockIdx.x & 63;
    const int u  = threadIdx.x;          // 0..895 = 224 rows x 4 chunks
    const int r  = u >> 2;               // row: g*32+n
    const int pc = u & 3;
    const int koct = pc ^ ((r >> 1) & 3);
    const int g  = r >> 5;
    const int n  = r & 31;
    const int col = g * H_SZ + by * BN + n;
    const float* src = W + (size_t)(ks * BK + koct * 8) * NW + col;
    float w0 = src[0];
    float w1 = src[(size_t)NW];
    float w2 = src[(size_t)2 * NW];
    float w3 = src[(size_t)3 * NW];
    float w4 = src[(size_t)4 * NW];
    float w5 = src[(size_t)5 * NW];
    float w6 = src[(size_t)6 * NW];
    float w7 = src[(size_t)7 * NW];
    uint4 o;
    o.x = cvtpk(w0, w1); o.y = cvtpk(w2, w3);
    o.z = cvtpk(w4, w5); o.w = cvtpk(w6, w7);
    *(uint4*)(wb + (size_t)blockIdx.x * 14336 + u * 16) = o;
}

// ---------------- convert hx -> hx' (bf16, PLAIN layout) -------------------
__global__ __launch_bounds__(1024) void conv_hx(const float* __restrict__ hx,
                                                char* __restrict__ hxb)
{
    const int bx = blockIdx.x >> 6;
    const int ks = blockIdx.x & 63;
    const int u  = threadIdx.x;          // 0..1023 = 256 rows x 4 chunks
    const int r  = u >> 2;
    const int pc = u & 3;                // plain: chunk pc = k-octet pc
    const float* src = hx + (size_t)(bx * BM + r) * D_SZ + ks * BK + pc * 8;
    f32x4 a = *(const f32x4*)(src);
    f32x4 b = *(const f32x4*)(src + 4);
    uint4 o;
    o.x = cvtpk(a[0], a[1]); o.y = cvtpk(a[2], a[3]);
    o.z = cvtpk(b[0], b[1]); o.w = cvtpk(b[2], b[3]);
    *(uint4*)(hxb + (size_t)blockIdx.x * 16384 + u * 16) = o;
}

// ---------------- main bf16 kernel -----------------------------------------
#define NTH3 1024
#define BUFB 14336                     // B-only buffers
#define NBUF 3

#define SB0 __builtin_amdgcn_sched_barrier(0)

__global__ __launch_bounds__(NTH3, 4) void lstm_bf16(
    const char* __restrict__ wb, const char* __restrict__ hxb,
    const float* __restrict__ cx1, const float* __restrict__ cx2,
    const float* __restrict__ dt, const float* __restrict__ bias,
    float* __restrict__ out)
{
    __shared__ char smem[NBUF * BUFB];   // 43008 B

    const int tid  = threadIdx.x;
    const int lane = tid & 63;
    const int wid  = tid >> 6;           // 0..15
    const int wm   = wid >> 1;           // 0..7  (32 rows each)
    const int wn   = wid & 1;            // 0..1  (16 cols each)
    const int l15  = lane & 15;
    const int lg   = lane >> 4;

    // block order: XCD chunk, then by-pairs (W panel stays L2-hot)
    const int b0  = blockIdx.x;
    const int swz = (b0 & 7) * 256 + (b0 >> 3);
    const int by2 = swz >> 6;            // 0..31
    const int rem = swz & 63;
    const int bx  = rem >> 1;            // 0..31
    const int by  = by2 * 2 + (rem & 1); // 0..63
    const int gm0 = bx * BM;
    const int n0  = by * BN;

    // A: per-wave direct-global pointer (coalesced 1KB per fragment load)
    const char* pa = hxb + ((size_t)(bx * NKST) << 14)
                   + (wm * 32 + l15) * 64 + lg * 16;
    // B: staging source pointer (starts at tile 2; tiles 0,1 in prologue)
    const char* wbase = wb + (size_t)(by * NKST) * 14336;
    const int stG = (wid << 10) + (lane << 4);   // per-lane global offset
    const int stL = (wid << 10);                 // wave-uniform LDS offset
    const char* pw = wbase + 2 * 14336 + stG;

    // B fragment read offset (ushort units), XOR chunk = lg ^ ((l15>>1)&3)
    const int boffu = (wn * 16 + l15) * 32 + (lg ^ ((l15 >> 1) & 3)) * 8;

    f32x4 acc[NG][2];
    #pragma unroll
    for (int g = 0; g < NG; ++g) {
        acc[g][0] = (f32x4){0.f, 0.f, 0.f, 0.f};
        acc[g][1] = (f32x4){0.f, 0.f, 0.f, 0.f};
    }

    // prologue: stage tiles 0,1 into bufs 0,1
    if (wid < 14) {
        glds16(wbase + stG, smem + stL);
        glds16(wbase + 14336 + stG, smem + BUFB + stL);
    }

    // Per step t: vmcnt(1) drains glds(t) [glds(t+1) stays in flight];
    // barrier publishes buf(t). Compiler-tracked A-loads (vmem) and B
    // ds_reads (lgkm) are drained by the compiler's own counted waits
    // before the MFMA cluster; A issued before glds keeps counters disjoint.
    #define BODY(CUR, NXT, VMN, STG) do {                                      \
        asm volatile("s_waitcnt vmcnt(" #VMN ")" ::: "memory");                \
        __builtin_amdgcn_s_barrier();                                          \
        SB0;                                                                   \
        bf16x8 bfr[NG];                                                        \
        const ushort* sb_ = (const ushort*)(smem + (CUR) * BUFB) + boffu;      \
        _Pragma("unroll")                                                      \
        for (int g_ = 0; g_ < NG; ++g_)                                        \
            bfr[g_] = *(const bf16x8*)(sb_ + g_ * 1024);                       \
        bf16x8 a0_ = *(const bf16x8*)(pa);                                     \
        bf16x8 a1_ = *(const bf16x8*)(pa + 1024);                              \
        SB0;                                                                   \
        if ((STG) && wid < 14) glds16(pw, smem + (NXT) * BUFB + stL);          \
        SB0;                                                                   \
        __builtin_amdgcn_s_setprio(1);                                         \
        _Pragma("unroll")                                                      \
        for (int g_ = 0; g_ < NG; ++g_) {                                      \
            acc[g_][0] = __builtin_amdgcn_mfma_f32_16x16x32_bf16(              \
                a0_, bfr[g_], acc[g_][0], 0, 0, 0);                            \
            acc[g_][1] = __builtin_amdgcn_mfma_f32_16x16x32_bf16(              \
                a1_, bfr[g_], acc[g_][1], 0, 0, 0);                            \
        }                                                                      \
        __builtin_amdgcn_s_setprio(0);                                         \
        SB0;                                                                   \
        pa += 16384; pw += 14336;                                              \
    } while (0)

    // t = 0..59 (20 x unroll-3, buffers mod-3), staging tiles 2..61
    #pragma unroll 1
    for (int it = 0; it < 20; ++it) {
        BODY(0, 2, 1, 1);
        BODY(1, 0, 1, 1);
        BODY(2, 1, 1, 1);
    }
    BODY(0, 2, 1, 1);   // t=60, stages tile 62 -> buf2
    BODY(1, 0, 1, 1);   // t=61, stages tile 63 -> buf0
    BODY(2, 1, 1, 0);   // t=62 (drains glds(62))
    BODY(0, 0, 0, 0);   // t=63 (drains glds(63))

    // epilogue: all 7 gate pre-activations in registers
    const size_t BH = (size_t)B_SZ * H_SZ;
    const int j = n0 + wn * 16 + l15;
    float bj[NG];
    #pragma unroll
    for (int g = 0; g < NG; ++g) bj[g] = bias[g * H_SZ + j];

    #pragma unroll
    for (int mf = 0; mf < 2; ++mf) {
        #pragma unroll
        for (int r = 0; r < 4; ++r) {
            int row = gm0 + wm * 32 + mf * 16 + lg * 4 + r;
            float dtv = dt[row];
            float i1 = sigmoidf_(acc[0][mf][r] + bj[0]);
            float i2 = sigmoidf_(acc[1][mf][r] + bj[1]);
            float f1 = sigmoidf_(acc[2][mf][r] + bj[2]);
            float f2 = sigmoidf_(acc[3][mf][r] + bj[3]);
            float o  = sigmoidf_(acc[4][mf][r] + bj[4]);
            float z  = tanhf_(acc[5][mf][r] + bj[5]);
            float dec = softplusf_(acc[6][mf][r] + bj[6]);
            size_t idx = (size_t)row * H_SZ + j;
            float c1 = cx1[idx], c2 = cx2[idx];
            float cy1 = f1 * c1 + i1 * z;
            float cy2 = f2 * c2 + i2 * z;
            float ct  = cy2 + (cy1 - cy2) * __expf(-dec * dtv);
            float ht  = o * tanhf_(ct);
            out[idx]          = cy1;
            out[BH + idx]     = cy2;
            out[2 * BH + idx] = ht;
        }
    }
    #undef BODY
}

// ---------------- f32 fallback (R2, passed) --------------------------------
#define NTH  512
#define LDP  40
__global__ __launch_bounds__(NTH, 2) void lstm_f32(
    const float* __restrict__ hx, const float* __restrict__ cx1,
    const float* __restrict__ cx2, const float* __restrict__ dt,
    const float* __restrict__ W, const float* __restrict__ bias,
    float* __restrict__ out)
{
    __shared__ ushort sA[BM * LDP];
    __shared__ ushort sB[NG * BN * LDP];

    const int tid = threadIdx.x;
    const int nwg = gridDim.x;
    const int cpx = nwg >> 3;
    const int b0  = blockIdx.x;
    const int swz = (b0 & 7) * cpx + (b0 >> 3);
    const int bx  = swz & 31;
    const int by  = swz >> 5;
    const int gm0 = bx * BM;
    const int n0  = by * BN;

    const int lane = tid & 63;
    const int wid  = tid >> 6;
    const int wm   = wid >> 1;
    const int wn   = wid & 1;
    const int l15  = lane & 15;
    const int lg   = lane >> 4;

    const int ar0 = tid >> 2,          aq0 = tid & 3;
    const int ar1 = (tid + 512) >> 2,  aq1 = tid & 3;
    const bool hasB = (tid < 448);
    const int bg  = tid >> 6;
    const int bkq = (tid >> 3) & 7;
    const int bnq = tid & 7;

    f32x4 pa[4];
    f32x4 pb[4];

    auto issue_loads = [&](int K0) {
        {
            const float* p = hx + (size_t)(gm0 + ar0) * D_SZ + K0 + aq0 * 8;
            pa[0] = *(const f32x4*)(p);
            pa[1] = *(const f32x4*)(p + 4);
        }
        {
            const float* p = hx + (size_t)(gm0 + ar1) * D_SZ + K0 + aq1 * 8;
            pa[2] = *(const f32x4*)(p);
            pa[3] = *(const f32x4*)(p + 4);
        }
        if (hasB) {
            const float* p = W + (size_t)(K0 + bkq * 4) * NW + bg * H_SZ + n0 + bnq * 4;
            pb[0] = *(const f32x4*)(p);
            pb[1] = *(const f32x4*)(p + NW);
            pb[2] = *(const f32x4*)(p + 2 * NW);
            pb[3] = *(const f32x4*)(p + 3 * NW);
        }
    };

    auto store_lds = [&]() {
        {
            uint4 u;
            u.x = cvtpk(pa[0][0], pa[0][1]); u.y = cvtpk(pa[0][2], pa[0][3]);
            u.z = cvtpk(pa[1][0], pa[1][1]); u.w = cvtpk(pa[1][2], pa[1][3]);
            *(uint4*)(&sA[ar0 * LDP + aq0 * 8]) = u;
        }
        {
            uint4 u;
            u.x = cvtpk(pa[2][0], pa[2][1]); u.y = cvtpk(pa[2][2], pa[2][3]);
            u.z = cvtpk(pa[3][0], pa[3][1]); u.w = cvtpk(pa[3][2], pa[3][3]);
            *(uint4*)(&sA[ar1 * LDP + aq1 * 8]) = u;
        }
        if (hasB) {
            #pragma unroll
            for (int jj = 0; jj < 4; ++jj) {
                uint2 v;
                v.x = cvtpk(pb[0][jj], pb[1][jj]);
                v.y = cvtpk(pb[2][jj], pb[3][jj]);
                *(uint2*)(&sB[(bg * BN + bnq * 4 + jj) * LDP + bkq * 4]) = v;
            }
        }
    };

    f32x4 acc[NG][4];
    #pragma unroll
    for (int g = 0; g < NG; ++g)
        #pragma unroll
        for (int mf = 0; mf < 4; ++mf)
            acc[g][mf] = (f32x4){0.f, 0.f, 0.f, 0.f};

    int aoff[4];
    #pragma unroll
    for (int mf = 0; mf < 4; ++mf)
        aoff[mf] = (wm * 64 + mf * 16 + l15) * LDP + lg * 8;
    int boff[NG];
    #pragma unroll
    for (int g = 0; g < NG; ++g)
        boff[g] = (g * BN + wn * 16 + l15) * LDP + lg * 8;

    issue_loads(0);
    for (int kk = 0; kk < NKST; ++kk) {
        store_lds();
        __syncthreads();
        if (kk + 1 < NKST) issue_loads((kk + 1) * BK);

        bf16x8 af[4];
        #pragma unroll
        for (int mf = 0; mf < 4; ++mf)
            af[mf] = *(const bf16x8*)(&sA[aoff[mf]]);
        #pragma unroll
        for (int g = 0; g < NG; ++g) {
            bf16x8 bfr = *(const bf16x8*)(&sB[boff[g]]);
            #pragma unroll
            for (int mf = 0; mf < 4; ++mf)
                acc[g][mf] = __builtin_amdgcn_mfma_f32_16x16x32_bf16(
                    af[mf], bfr, acc[g][mf], 0, 0, 0);
        }
        __syncthreads();
    }

    const size_t BH = (size_t)B_SZ * H_SZ;
    const int j = n0 + wn * 16 + l15;
    float bj[NG];
    #pragma unroll
    for (int g = 0; g < NG; ++g) bj[g] = bias[g * H_SZ + j];

    #pragma unroll
    for (int mf = 0; mf < 4; ++mf) {
        #pragma unroll
        for (int r = 0; r < 4; ++r) {
            int row = gm0 + wm * 64 + mf * 16 + lg * 4 + r;
            float dtv = dt[row];
            float i1 = sigmoidf_(acc[0][mf][r] + bj[0]);
            float i2 = sigmoidf_(acc[1][mf][r] + bj[1]);
            float f1 = sigmoidf_(acc[2][mf][r] + bj[2]);
            float f2 = sigmoidf_(acc[3][mf][r] + bj[3]);
            float o  = sigmoidf_(acc[4][mf][r] + bj[4]);
            float z  = tanhf_(acc[5][mf][r] + bj[5]);
            float dec = softplusf_(acc[6][mf][r] + bj[6]);
            size_t idx = (size_t)row * H_SZ + j;
            float c1 = cx1[idx], c2 = cx2[idx];
            float cy1 = f1 * c1 + i1 * z;
            float cy2 = f2 * c2 + i2 * z;
            float ct  = cy2 + (cy1 - cy2) * __expf(-dec * dtv);
            float ht  = o * tanhf_(ct);
            out[idx]          = cy1;
            out[BH + idx]     = cy2;
            out[2 * BH + idx] = ht;
        }
    }
}

extern "C" void kernel_launch(void* const* d_in, const int* in_sizes, int n_in,
                              void* d_out, int out_size, void* d_ws, size_t ws_size,
                              hipStream_t stream) {
    const float* hx  = (const float*)d_in[0];
    const float* cx1 = (const float*)d_in[1];
    const float* cx2 = (const float*)d_in[2];
    const float* dt  = (const float*)d_in[4];
    const float* W   = (const float*)d_in[5];
    const float* b   = (const float*)d_in[6];
    float* out = (float*)d_out;

    if (ws_size >= WS_NEEDED) {
        char* wb  = (char*)d_ws;
        char* hxb = (char*)d_ws + HXB_OFF;
        conv_w<<<dim3(NBY * NKST), dim3(896), 0, stream>>>(W, wb);
        conv_hx<<<dim3(NBX * NKST), dim3(1024), 0, stream>>>(hx, hxb);
        lstm_bf16<<<dim3(NBX * NBY), dim3(NTH3), 0, stream>>>(
            wb, hxb, cx1, cx2, dt, b, out);
    } else {
        lstm_f32<<<dim3(NBX * NBY), dim3(NTH), 0, stream>>>(
            hx, cx1, cx2, dt, W, b, out);
    }
}

// Round 10
// 534.816 us; speedup vs baseline: 1.2099x; 1.2099x over previous
//
#include <hip/hip_runtime.h>
#include <hip/hip_bf16.h>
#include <stdint.h>

// LSTMCell fused: g = hx @ W + b (M=8192,K=2048,N=7*2048) + gate math.
// R10: Mw=64 (8 waves, 2/SIMD) with an in-order-lgkm-correct register
// pipeline: per step, 11 asm ds_read_b128 issued front (A t.1-3, B t+1 x7,
// A t+1.0), then 4 MFMA clusters gated by COUNTED lgkmcnt(11/10/9/8) --
// LDS service overlaps the matrix pipe within each wave. B/A0 parity
// double-buffered only (arch ~110 regs, no spill). glds depth-3, vmcnt(4).

#define B_SZ 8192
#define D_SZ 2048
#define H_SZ 2048
#define NG   7
#define NW   (NG * H_SZ)          // 14336
#define BM   256
#define BN   32
#define BK   32
#define NKST (D_SZ / BK)          // 64
#define NBX  (B_SZ / BM)          // 32
#define NBY  (H_SZ / BN)          // 64

// bf16 tile images in ws:
//  W' : [by(64)][ks(64)] -> 224 rows x 32 k bf16 = 14336 B (XOR-swizzled)
//  hx': [bx(32)][ks(64)] -> 256 rows x 32 k bf16 = 16384 B (XOR-swizzled)
// Within a tile: row-major, 64 B/row, 16B chunk pc stores logical k-octet
// koct = pc ^ ((r>>1)&3).
#define WB_BYTES   ((size_t)NBY * NKST * 14336)   // 58,720,256
#define HXB_OFF    WB_BYTES
#define HXB_BYTES  ((size_t)NBX * NKST * 16384)   // 33,554,432
#define WS_NEEDED  (WB_BYTES + HXB_BYTES)         // 92,274,688

typedef __attribute__((ext_vector_type(8))) short bf16x8;
typedef __attribute__((ext_vector_type(4))) float f32x4;

__device__ __forceinline__ uint32_t cvtpk(float lo, float hi) {
    uint32_t r;
    asm("v_cvt_pk_bf16_f32 %0, %1, %2" : "=v"(r) : "v"(lo), "v"(hi));
    return r;
}
__device__ __forceinline__ void glds16(const void* g, void* l) {
    __builtin_amdgcn_global_load_lds(
        (const __attribute__((address_space(1))) uint32_t*)g,
        (__attribute__((address_space(3))) uint32_t*)l, 16, 0, 0);
}
__device__ __forceinline__ float sigmoidf_(float x) {
    return 1.0f / (1.0f + __expf(-x));
}
__device__ __forceinline__ float tanhf_(float x) {
    float ax = fabsf(x);
    float e = __expf(2.0f * ax);
    float t = 1.0f - 2.0f / (e + 1.0f);
    return copysignf(t, x);
}
__device__ __forceinline__ float softplusf_(float x) {
    return (x > 30.0f) ? x : __logf(1.0f + __expf(x));
}

// ---------------- convert W -> W' (bf16, transposed, swizzled) -------------
__global__ __launch_bounds__(896) void conv_w(const float* __restrict__ W,
                                              char* __restrict__ wb)
{
    const int by = blockIdx.x >> 6;
    const int ks = blockIdx.x & 63;
    const int u  = threadIdx.x;          // 0..895 = 224 rows x 4 chunks
    const int r  = u >> 2;               // row: g*32+n
    const int pc = u & 3;
    const int koct = pc ^ ((r >> 1) & 3);
    const int g  = r >> 5;
    const int n  = r & 31;
    const int col = g * H_SZ + by * BN + n;
    const float* src = W + (size_t)(ks * BK + koct * 8) * NW + col;
    float w0 = src[0];
    float w1 = src[(size_t)NW];
    float w2 = src[(size_t)2 * NW];
    float w3 = src[(size_t)3 * NW];
    float w4 = src[(size_t)4 * NW];
    float w5 = src[(size_t)5 * NW];
    float w6 = src[(size_t)6 * NW];
    float w7 = src[(size_t)7 * NW];
    uint4 o;
    o.x = cvtpk(w0, w1); o.y = cvtpk(w2, w3);
    o.z = cvtpk(w4, w5); o.w = cvtpk(w6, w7);
    *(uint4*)(wb + (size_t)blockIdx.x * 14336 + u * 16) = o;
}

// ---------------- convert hx -> hx' (bf16, swizzled) -----------------------
__global__ __launch_bounds__(1024) void conv_hx(const float* __restrict__ hx,
                                                char* __restrict__ hxb)
{
    const int bx = blockIdx.x >> 6;
    const int ks = blockIdx.x & 63;
    const int u  = threadIdx.x;          // 0..1023 = 256 rows x 4 chunks
    const int r  = u >> 2;
    const int pc = u & 3;
    const int koct = pc ^ ((r >> 1) & 3);
    const float* src = hx + (size_t)(bx * BM + r) * D_SZ + ks * BK + koct * 8;
    f32x4 a = *(const f32x4*)(src);
    f32x4 b = *(const f32x4*)(src + 4);
    uint4 o;
    o.x = cvtpk(a[0], a[1]); o.y = cvtpk(a[2], a[3]);
    o.z = cvtpk(b[0], b[1]); o.w = cvtpk(b[2], b[3]);
    *(uint4*)(hxb + (size_t)blockIdx.x * 16384 + u * 16) = o;
}

// ---------------- main bf16 kernel -----------------------------------------
#define NTH3 512
#define BUFB 30720                     // 16384 (A) + 14336 (B)

#define SB0 __builtin_amdgcn_sched_barrier(0)

__global__ __launch_bounds__(NTH3, 2) void lstm_bf16(
    const char* __restrict__ wb, const char* __restrict__ hxb,
    const float* __restrict__ cx1, const float* __restrict__ cx2,
    const float* __restrict__ dt, const float* __restrict__ bias,
    float* __restrict__ out)
{
    __shared__ char smem[4 * BUFB];   // 122880 B

    const int tid  = threadIdx.x;
    const int lane = tid & 63;
    const int wid  = tid >> 6;           // 0..7
    const int wm   = wid >> 1;           // 0..3  (64 rows each)
    const int wn   = wid & 1;            // 0..1  (16 cols/gate each)
    const int l15  = lane & 15;
    const int lg   = lane >> 4;

    // block order: XCD chunk, then by-pairs
    const int b0  = blockIdx.x;
    const int swz = (b0 & 7) * 256 + (b0 >> 3);
    const int by2 = swz >> 6;
    const int rem = swz & 63;
    const int bx  = rem >> 1;
    const int by  = by2 * 2 + (rem & 1);
    const int gm0 = bx * BM;
    const int n0  = by * BN;

    // fragment LDS byte addresses, XOR chunk = lg ^ ((l15>>1)&3)
    const int xch = (lg ^ ((l15 >> 1) & 3)) * 8;
    const uint32_t aAb = (uint32_t)(uintptr_t)smem + 2u * ((wm * 64 + l15) * 32 + xch);
    const uint32_t aBb = (uint32_t)(uintptr_t)smem + 16384u + 2u * ((wn * 16 + l15) * 32 + xch);
    const uint32_t aA0 = aAb,            aA1 = aAb + BUFB;
    const uint32_t aA2 = aAb + 2 * BUFB, aA3 = aAb + 3 * BUFB;
    const uint32_t aB0 = aBb,            aB1 = aBb + BUFB;
    const uint32_t aB2 = aBb + 2 * BUFB, aB3 = aBb + 3 * BUFB;

    // staging (R5 pattern: 4 glds/wave/stage, uniform vmcnt)
    const int lane16 = lane << 4;
    const char* hxp0 = hxb + (((size_t)(bx * NKST)) << 14) + (wid << 11) + lane16;
    const char* wbp0 = wb + (size_t)(by * NKST) * 14336 + wid * 1792 + lane16;
    char* dA0 = smem + (wid << 11);            char* dB0 = smem + 16384 + wid * 1792;
    char* dA1 = dA0 + BUFB;                    char* dB1 = dB0 + BUFB;
    char* dA2 = dA0 + 2 * BUFB;                char* dB2 = dB0 + 2 * BUFB;
    char* dA3 = dA0 + 3 * BUFB;                char* dB3 = dB0 + 3 * BUFB;

    f32x4 acc[NG][4];
    #pragma unroll
    for (int g = 0; g < NG; ++g)
        #pragma unroll
        for (int mf = 0; mf < 4; ++mf)
            acc[g][mf] = (f32x4){0.f, 0.f, 0.f, 0.f};

    // fragment registers: B and A0 parity double-buffered; A1-3 single
    bf16x8 fBE[NG], fBO[NG];
    bf16x8 fA0E, fA0O, fA1, fA2, fA3;

    #define ISSUE_A123(AAc) do {                                                   \
        asm volatile("ds_read_b128 %0, %1 offset:1024" : "=&v"(fA1) : "v"(AAc));   \
        asm volatile("ds_read_b128 %0, %1 offset:2048" : "=&v"(fA2) : "v"(AAc));   \
        asm volatile("ds_read_b128 %0, %1 offset:3072" : "=&v"(fA3) : "v"(AAc));   \
    } while (0)

    #define ISSUE_NEXT(ABn, AAn, FBN, FA0N) do {                                   \
        asm volatile("ds_read_b128 %0, %1"               : "=&v"(FBN[0]) : "v"(ABn)); \
        asm volatile("ds_read_b128 %0, %1 offset:2048"   : "=&v"(FBN[1]) : "v"(ABn)); \
        asm volatile("ds_read_b128 %0, %1 offset:4096"   : "=&v"(FBN[2]) : "v"(ABn)); \
        asm volatile("ds_read_b128 %0, %1 offset:6144"   : "=&v"(FBN[3]) : "v"(ABn)); \
        asm volatile("ds_read_b128 %0, %1 offset:8192"   : "=&v"(FBN[4]) : "v"(ABn)); \
        asm volatile("ds_read_b128 %0, %1 offset:10240"  : "=&v"(FBN[5]) : "v"(ABn)); \
        asm volatile("ds_read_b128 %0, %1 offset:12288"  : "=&v"(FBN[6]) : "v"(ABn)); \
        asm volatile("ds_read_b128 %0, %1"               : "=&v"(FA0N)   : "v"(AAn)); \
    } while (0)

    #define CLUSTER(FA, FBC, MF, LGN) do {                                         \
        asm volatile("s_waitcnt lgkmcnt(" #LGN ")" ::: "memory");                  \
        SB0;                                                                       \
        __builtin_amdgcn_s_setprio(1);                                             \
        _Pragma("unroll")                                                          \
        for (int g_ = 0; g_ < NG; ++g_)                                            \
            acc[g_][MF] = __builtin_amdgcn_mfma_f32_16x16x32_bf16(                 \
                FA, FBC[g_], acc[g_][MF], 0, 0, 0);                                \
        __builtin_amdgcn_s_setprio(0);                                             \
        SB0;                                                                       \
    } while (0)

    #define STAGE(SC) do {                                                         \
        glds16(hxp, dA##SC); glds16(hxp + 1024, dA##SC + 1024);                    \
        glds16(wbp, dB##SC);                                                       \
        if (lane < 48) glds16(wbp + 1024, dB##SC + 1024);                          \
        hxp += 16384; wbp += 14336;                                                \
    } while (0)

    #define STAGE_K(SC, K) do {                                                    \
        glds16(hxp0 + (K) * 16384, dA##SC);                                        \
        glds16(hxp0 + (K) * 16384 + 1024, dA##SC + 1024);                          \
        glds16(wbp0 + (K) * 14336, dB##SC);                                        \
        if (lane < 48) glds16(wbp0 + (K) * 14336 + 1024, dB##SC + 1024);           \
    } while (0)

    // Steady step t (c = t&3, cn = (t+1)&3, parity P):
    //  entry lgkm outstanding: {B(t)x7, A(t,0)} = 8; glds: {t+1:4, t+2:4}.
    //  vmcnt(4)+barrier publishes tile t+1; issue A(t,1-3) [c], B(t+1)+A0 [cn];
    //  stage(t+3) -> buf[(t+3)&3]; clusters gated lgkm 11/10/9/8.
    #define STEP_S(AAc, ABn, AAn, FBC, FBN, FA0C, FA0N, SC, VMN)  do {             \
        asm volatile("s_waitcnt vmcnt(" #VMN ")" ::: "memory");                    \
        __builtin_amdgcn_s_barrier();                                              \
        SB0;                                                                       \
        ISSUE_A123(AAc);                                                           \
        ISSUE_NEXT(ABn, AAn, FBN, FA0N);                                           \
        SB0;                                                                       \
        STAGE(SC);                                                                 \
        SB0;                                                                       \
        CLUSTER(FA0C, FBC, 0, 11);                                                 \
        CLUSTER(fA1,  FBC, 1, 10);                                                 \
        CLUSTER(fA2,  FBC, 2, 9);                                                  \
        CLUSTER(fA3,  FBC, 3, 8);                                                  \
    } while (0)

    #define STEP_N(AAc, ABn, AAn, FBC, FBN, FA0C, FA0N, VMN)  do {                 \
        asm volatile("s_waitcnt vmcnt(" #VMN ")" ::: "memory");                    \
        __builtin_amdgcn_s_barrier();                                              \
        SB0;                                                                       \
        ISSUE_A123(AAc);                                                           \
        ISSUE_NEXT(ABn, AAn, FBN, FA0N);                                           \
        SB0;                                                                       \
        CLUSTER(FA0C, FBC, 0, 11);                                                 \
        CLUSTER(fA1,  FBC, 1, 10);                                                 \
        CLUSTER(fA2,  FBC, 2, 9);                                                  \
        CLUSTER(fA3,  FBC, 3, 8);                                                  \
    } while (0)

    // prologue: stage tiles 0..2; publish tile 0; issue B(0)+A(0,0) -> E set
    STAGE_K(0, 0);
    STAGE_K(1, 1);
    STAGE_K(2, 2);
    const char* hxp = hxp0 + 3 * 16384;
    const char* wbp = wbp0 + 3 * 14336;
    asm volatile("s_waitcnt vmcnt(8)" ::: "memory");
    __builtin_amdgcn_s_barrier();
    SB0;
    ISSUE_NEXT(aB0, aA0, fBE, fA0E);
    SB0;

    // steady: t = 0..59 (15 x 4)
    #pragma unroll 1
    for (int it = 0; it < 15; ++it) {
        STEP_S(aA0, aB1, aA1, fBE, fBO, fA0E, fA0O, 3, 4);   // t%4==0 (E)
        STEP_S(aA1, aB2, aA2, fBO, fBE, fA0O, fA0E, 0, 4);   // t%4==1 (O)
        STEP_S(aA2, aB3, aA3, fBE, fBO, fA0E, fA0O, 1, 4);   // t%4==2 (E)
        STEP_S(aA3, aB0, aA0, fBO, fBE, fA0O, fA0E, 2, 4);   // t%4==3 (O)
    }
    // t=60 (E): stages tile 63 -> buf3
    STEP_S(aA0, aB1, aA1, fBE, fBO, fA0E, fA0O, 3, 4);
    // t=61 (O): no stage; vmcnt(4) publishes tile 62
    STEP_N(aA1, aB2, aA2, fBO, fBE, fA0O, fA0E, 4);
    // t=62 (E): vmcnt(0) publishes tile 63
    STEP_N(aA2, aB3, aA3, fBE, fBO, fA0E, fA0O, 0);
    // t=63 (O): final — only A123; counted drains 3/2/1/0
    ISSUE_A123(aA3);
    SB0;
    CLUSTER(fA0O, fBO, 0, 3);
    CLUSTER(fA1,  fBO, 1, 2);
    CLUSTER(fA2,  fBO, 2, 1);
    CLUSTER(fA3,  fBO, 3, 0);

    // epilogue
    const size_t BH = (size_t)B_SZ * H_SZ;
    const int j = n0 + wn * 16 + l15;
    float bj[NG];
    #pragma unroll
    for (int g = 0; g < NG; ++g) bj[g] = bias[g * H_SZ + j];

    #pragma unroll
    for (int mf = 0; mf < 4; ++mf) {
        #pragma unroll
        for (int r = 0; r < 4; ++r) {
            int row = gm0 + wm * 64 + mf * 16 + lg * 4 + r;
            float dtv = dt[row];
            float i1 = sigmoidf_(acc[0][mf][r] + bj[0]);
            float i2 = sigmoidf_(acc[1][mf][r] + bj[1]);
            float f1 = sigmoidf_(acc[2][mf][r] + bj[2]);
            float f2 = sigmoidf_(acc[3][mf][r] + bj[3]);
            float o  = sigmoidf_(acc[4][mf][r] + bj[4]);
            float z  = tanhf_(acc[5][mf][r] + bj[5]);
            float dec = softplusf_(acc[6][mf][r] + bj[6]);
            size_t idx = (size_t)row * H_SZ + j;
            float c1 = cx1[idx], c2 = cx2[idx];
            float cy1 = f1 * c1 + i1 * z;
            float cy2 = f2 * c2 + i2 * z;
            float ct  = cy2 + (cy1 - cy2) * __expf(-dec * dtv);
            float ht  = o * tanhf_(ct);
            out[idx]          = cy1;
            out[BH + idx]     = cy2;
            out[2 * BH + idx] = ht;
        }
    }
}

// ---------------- f32 fallback (R2, passed) --------------------------------
#define NTH  512
#define LDP  40
__global__ __launch_bounds__(NTH, 2) void lstm_f32(
    const float* __restrict__ hx, const float* __restrict__ cx1,
    const float* __restrict__ cx2, const float* __restrict__ dt,
    const float* __restrict__ W, const float* __restrict__ bias,
    float* __restrict__ out)
{
    __shared__ ushort sA[BM * LDP];
    __shared__ ushort sB[NG * BN * LDP];

    const int tid = threadIdx.x;
    const int nwg = gridDim.x;
    const int cpx = nwg >> 3;
    const int b0  = blockIdx.x;
    const int swz = (b0 & 7) * cpx + (b0 >> 3);
    const int bx  = swz & 31;
    const int by  = swz >> 5;
    const int gm0 = bx * BM;
    const int n0  = by * BN;

    const int lane = tid & 63;
    const int wid  = tid >> 6;
    const int wm   = wid >> 1;
    const int wn   = wid & 1;
    const int l15  = lane & 15;
    const int lg   = lane >> 4;

    const int ar0 = tid >> 2,          aq0 = tid & 3;
    const int ar1 = (tid + 512) >> 2,  aq1 = tid & 3;
    const bool hasB = (tid < 448);
    const int bg  = tid >> 6;
    const int bkq = (tid >> 3) & 7;
    const int bnq = tid & 7;

    f32x4 pa[4];
    f32x4 pb[4];

    auto issue_loads = [&](int K0) {
        {
            const float* p = hx + (size_t)(gm0 + ar0) * D_SZ + K0 + aq0 * 8;
            pa[0] = *(const f32x4*)(p);
            pa[1] = *(const f32x4*)(p + 4);
        }
        {
            const float* p = hx + (size_t)(gm0 + ar1) * D_SZ + K0 + aq1 * 8;
            pa[2] = *(const f32x4*)(p);
            pa[3] = *(const f32x4*)(p + 4);
        }
        if (hasB) {
            const float* p = W + (size_t)(K0 + bkq * 4) * NW + bg * H_SZ + n0 + bnq * 4;
            pb[0] = *(const f32x4*)(p);
            pb[1] = *(const f32x4*)(p + NW);
            pb[2] = *(const f32x4*)(p + 2 * NW);
            pb[3] = *(const f32x4*)(p + 3 * NW);
        }
    };

    auto store_lds = [&]() {
        {
            uint4 u;
            u.x = cvtpk(pa[0][0], pa[0][1]); u.y = cvtpk(pa[0][2], pa[0][3]);
            u.z = cvtpk(pa[1][0], pa[1][1]); u.w = cvtpk(pa[1][2], pa[1][3]);
            *(uint4*)(&sA[ar0 * LDP + aq0 * 8]) = u;
        }
        {
            uint4 u;
            u.x = cvtpk(pa[2][0], pa[2][1]); u.y = cvtpk(pa[2][2], pa[2][3]);
            u.z = cvtpk(pa[3][0], pa[3][1]); u.w = cvtpk(pa[3][2], pa[3][3]);
            *(uint4*)(&sA[ar1 * LDP + aq1 * 8]) = u;
        }
        if (hasB) {
            #pragma unroll
            for (int jj = 0; jj < 4; ++jj) {
                uint2 v;
                v.x = cvtpk(pb[0][jj], pb[1][jj]);
                v.y = cvtpk(pb[2][jj], pb[3][jj]);
                *(uint2*)(&sB[(bg * BN + bnq * 4 + jj) * LDP + bkq * 4]) = v;
            }
        }
    };

    f32x4 acc[NG][4];
    #pragma unroll
    for (int g = 0; g < NG; ++g)
        #pragma unroll
        for (int mf = 0; mf < 4; ++mf)
            acc[g][mf] = (f32x4){0.f, 0.f, 0.f, 0.f};

    int aoff[4];
    #pragma unroll
    for (int mf = 0; mf < 4; ++mf)
        aoff[mf] = (wm * 64 + mf * 16 + l15) * LDP + lg * 8;
    int boff[NG];
    #pragma unroll
    for (int g = 0; g < NG; ++g)
        boff[g] = (g * BN + wn * 16 + l15) * LDP + lg * 8;

    issue_loads(0);
    for (int kk = 0; kk < NKST; ++kk) {
        store_lds();
        __syncthreads();
        if (kk + 1 < NKST) issue_loads((kk + 1) * BK);

        bf16x8 af[4];
        #pragma unroll
        for (int mf = 0; mf < 4; ++mf)
            af[mf] = *(const bf16x8*)(&sA[aoff[mf]]);
        #pragma unroll
        for (int g = 0; g < NG; ++g) {
            bf16x8 bfr = *(const bf16x8*)(&sB[boff[g]]);
            #pragma unroll
            for (int mf = 0; mf < 4; ++mf)
                acc[g][mf] = __builtin_amdgcn_mfma_f32_16x16x32_bf16(
                    af[mf], bfr, acc[g][mf], 0, 0, 0);
        }
        __syncthreads();
    }

    const size_t BH = (size_t)B_SZ * H_SZ;
    const int j = n0 + wn * 16 + l15;
    float bj[NG];
    #pragma unroll
    for (int g = 0; g < NG; ++g) bj[g] = bias[g * H_SZ + j];

    #pragma unroll
    for (int mf = 0; mf < 4; ++mf) {
        #pragma unroll
        for (int r = 0; r < 4; ++r) {
            int row = gm0 + wm * 64 + mf * 16 + lg * 4 + r;
            float dtv = dt[row];
            float i1 = sigmoidf_(acc[0][mf][r] + bj[0]);
            float i2 = sigmoidf_(acc[1][mf][r] + bj[1]);
            float f1 = sigmoidf_(acc[2][mf][r] + bj[2]);
            float f2 = sigmoidf_(acc[3][mf][r] + bj[3]);
            float o  = sigmoidf_(acc[4][mf][r] + bj[4]);
            float z  = tanhf_(acc[5][mf][r] + bj[5]);
            float dec = softplusf_(acc[6][mf][r] + bj[6]);
            size_t idx = (size_t)row * H_SZ + j;
            float c1 = cx1[idx], c2 = cx2[idx];
            float cy1 = f1 * c1 + i1 * z;
            float cy2 = f2 * c2 + i2 * z;
            float ct  = cy2 + (cy1 - cy2) * __expf(-dec * dtv);
            float ht  = o * tanhf_(ct);
            out[idx]          = cy1;
            out[BH + idx]     = cy2;
            out[2 * BH + idx] = ht;
        }
    }
}

extern "C" void kernel_launch(void* const* d_in, const int* in_sizes, int n_in,
                              void* d_out, int out_size, void* d_ws, size_t ws_size,
                              hipStream_t stream) {
    const float* hx  = (const float*)d_in[0];
    const float* cx1 = (const float*)d_in[1];
    const float* cx2 = (const float*)d_in[2];
    const float* dt  = (const float*)d_in[4];
    const float* W   = (const float*)d_in[5];
    const float* b   = (const float*)d_in[6];
    float* out = (float*)d_out;

    if (ws_size >= WS_NEEDED) {
        char* wb  = (char*)d_ws;
        char* hxb = (char*)d_ws + HXB_OFF;
        conv_w<<<dim3(NBY * NKST), dim3(896), 0, stream>>>(W, wb);
        conv_hx<<<dim3(NBX * NKST), dim3(1024), 0, stream>>>(hx, hxb);
        lstm_bf16<<<dim3(NBX * NBY), dim3(NTH3), 0, stream>>>(
            wb, hxb, cx1, cx2, dt, b, out);
    } else {
        lstm_f32<<<dim3(NBX * NBY), dim3(NTH), 0, stream>>>(
            hx, cx1, cx2, dt, W, b, out);
    }
}